// Round 6
// baseline (203.373 us; speedup 1.0000x reference)
//
#include <hip/hip_runtime.h>
#include <hip/hip_bf16.h>

// Problem constants (from reference)
#define NN 50000
#define EE 800000
#define INF_ 128
#define HH 4
#define FF 32
#define HF 128          // H*F
#define OUTC 160        // (H+1)*F per node
#define NEG_SLOPE 0.2f

#define CAP 64          // per-node bucket capacity; P(deg>64 | lambda=16) ~ 1e-19
#define CSTRIDE 16      // counts padded: one counter per 64B line (atomic line-serialization fix)

typedef __attribute__((ext_vector_type(8))) short short8;
typedef __attribute__((ext_vector_type(4))) float f32x4;
typedef _Float16 f16x2 __attribute__((ext_vector_type(2)));
typedef float fl2 __attribute__((ext_vector_type(2)));

// fp32 -> bf16 bits, round-to-nearest-even
__device__ __forceinline__ unsigned short f2bf(float f) {
    union { float f; unsigned u; } in; in.f = f;
    unsigned u = in.u;
    u += 0x7fffu + ((u >> 16) & 1u);
    return (unsigned short)(u >> 16);
}
__device__ __forceinline__ unsigned short f2h(float f) {
    _Float16 h = (_Float16)f;
    return __builtin_bit_cast(unsigned short, h);
}
__device__ __forceinline__ f16x2 bch(unsigned u) {
    return __builtin_bit_cast(f16x2, u);
}
__device__ __forceinline__ f16x2 habs2(f16x2 v) {
    unsigned u = __builtin_bit_cast(unsigned, v) & 0x7FFF7FFFu;
    return __builtin_bit_cast(f16x2, u);
}

// async global->LDS 16B copy: LDS dest = wave-uniform base + lane*16
__device__ __forceinline__ void async_cp16(const void* g, void* l) {
    __builtin_amdgcn_global_load_lds(
        (const __attribute__((address_space(1))) void*)g,
        (__attribute__((address_space(3))) void*)l, 16, 0, 0);
}

// ---------------- prep: weights transpose/swizzle + bias + attn + counts=0 -------
// Column order (n of 416), chosen so the edge-phase layout is produced directly:
//   n in [0,256):  pair-group g=n>>3, j=n&7; j<4 -> mut ch 4g+j, j>=4 -> self ch 4g+(j-4)
//   n in [256,384): er ch n-256
//   n in [384,416): lin ch n-384
__global__ __launch_bounds__(256) void prep_w(
    const float* __restrict__ W0, const float* __restrict__ b0,   // W_src_mut
    const float* __restrict__ W1, const float* __restrict__ b1,   // W_dst_mut (er)
    const float* __restrict__ W2, const float* __restrict__ b2,   // W_self
    const float* __restrict__ W3, const float* __restrict__ b3,   // W_lin
    const float* __restrict__ attn,
    unsigned short* __restrict__ WbT, float* __restrict__ biasc,
    unsigned short* __restrict__ ath, int* __restrict__ counts)
{
    int idx = blockIdx.x * 256 + threadIdx.x;   // 208 blocks -> 416*128 = 53248
    if (idx < NN) {
        // zero this node's private counter line (64B) -- fused memset
        uint4 z = make_uint4(0, 0, 0, 0);
        uint4* p = (uint4*)(counts + (size_t)idx * CSTRIDE);
        p[0] = z; p[1] = z; p[2] = z; p[3] = z;
    }
    int n = idx >> 7, k = idx & 127;
    float v;
    if (n < 256) {
        int g = n >> 3, j = n & 7;
        int ch = g * 4 + (j & 3);
        v = (j < 4) ? W0[k * 128 + ch] : W2[k * 128 + ch];
    } else if (n < 384) {
        v = W1[k * 128 + (n - 256)];
    } else {
        v = W3[k * 32 + (n - 384)];
    }
    int phys = (((k >> 3) ^ (n & 15)) << 3) | (k & 7);
    WbT[n * 128 + phys] = f2bf(v);
    if (idx < 416) {
        float bv;
        if (idx < 256) {
            int g = idx >> 3, j = idx & 7;
            int ch = g * 4 + (j & 3);
            bv = (j < 4) ? b0[ch] : b2[ch];
        } else if (idx < 384) {
            bv = b1[idx - 256];
        } else {
            bv = b3[idx - 384];
        }
        biasc[idx] = bv;
    }
    if (idx < 128) ath[idx] = f2h(attn[idx]);
}

// ---------------- fused GEMM + edge bucketing ------------------------------------
// grid (782, 4). Column split 112/96/112/96 -> LDS 44KB -> 3 blocks/CU.
// Edge handling is SPLIT: src/dst loads issued at block top (latency hidden under
// staging), atomicAdd + dependent random bucket store at the kernel TAIL so the
// atomic's latency never sits in front of the block's own MFMA barrier.
// counts are line-padded (CSTRIDE) so independent counters never share a 64B line.
// abs 16B chunk ca: 0..31 -> ms[N][256] (interleaved mut|self), 32..47 -> erh,
// 48..51 -> out fp32 (handled directly from acc in y=3).

template<int CPR, int CSTR, int CA0>
__device__ __forceinline__ void copy_out(
    const unsigned short* Cs, int row0, int tid,
    unsigned short* __restrict__ ms, unsigned short* __restrict__ erh)
{
    for (int c = tid; c < 64 * CPR; c += 256) {
        int row = c / CPR, c16 = c - row * CPR;
        int grow = row0 + row;
        if (grow >= NN) continue;
        uint4 v = *(const uint4*)(Cs + row * CSTR + c16 * 8);
        int ca = CA0 + c16;
        if (ca < 32) *(uint4*)(ms  + (size_t)grow * 256 + ca * 8) = v;
        else         *(uint4*)(erh + (size_t)grow * 128 + (ca - 32) * 8) = v;
    }
}

__global__ __launch_bounds__(256) void gemm_hist(
    const float* __restrict__ feat,
    const unsigned short* __restrict__ WbT,
    const float* __restrict__ biasc,
    const int* __restrict__ src, const int* __restrict__ dst,
    unsigned short* __restrict__ ms, unsigned short* __restrict__ erh,
    float* __restrict__ out,
    int* __restrict__ counts, int* __restrict__ srcbuck)
{
    __shared__ __align__(16) char lds[16384 + 28672];   // As 16KB | Bs 28KB
    unsigned short* As = (unsigned short*)lds;
    unsigned short* Bs = (unsigned short*)(lds + 16384);
    unsigned short* Cs = (unsigned short*)lds;           // aliases As post-MFMA (<=15.4KB)

    const int tid  = threadIdx.x;
    const int wv   = tid >> 6;
    const int lane = tid & 63;
    const int row0 = blockIdx.x * 64;
    const int yb   = blockIdx.y;

    // edge prefetch: issue src/dst loads NOW, consume at kernel tail
    const int e = (yb * 782 + blockIdx.x) * 256 + tid;
    int ed = 0, es = 0;
    if (e < EE) { ed = dst[e]; es = src[e]; }
    asm volatile("" :: "v"(ed), "v"(es));   // pin: force loads issued here

    const int ntile = (yb & 1) ? 6 : 7;                       // 16-col tiles this block
    const int base  = (yb == 0) ? 0 : (yb == 1) ? 112 : (yb == 2) ? 208 : 320;

    // stage B (async; WbT is pre-swizzled, LDS linear preserves swizzle)
    {
        const char* g = (const char*)(WbT + (size_t)base * 128);
        #pragma unroll
        for (int it = 0; it < 7; ++it) {
            if (it < ntile) {
                int seg = wv * ntile + it;
                async_cp16(g + seg * 1024 + lane * 16, (char*)Bs + seg * 1024);
            }
        }
    }
    // stage A: fp32 feat -> bf16 in regs, XOR-swizzled 16B chunks into LDS
    {
        #pragma unroll
        for (int i = 0; i < 4; ++i) {
            int idx = i * 256 + tid;           // 1024 chunks = 64 rows x 16
            int r = idx >> 4, c = idx & 15;
            int grow = row0 + r;
            float4 v0 = make_float4(0.f, 0.f, 0.f, 0.f), v1 = v0;
            if (grow < NN) {
                const float4* fp = (const float4*)(feat + (size_t)grow * 128 + c * 8);
                v0 = fp[0]; v1 = fp[1];
            }
            uint4 o;
            o.x = (unsigned)f2bf(v0.x) | ((unsigned)f2bf(v0.y) << 16);
            o.y = (unsigned)f2bf(v0.z) | ((unsigned)f2bf(v0.w) << 16);
            o.z = (unsigned)f2bf(v1.x) | ((unsigned)f2bf(v1.y) << 16);
            o.w = (unsigned)f2bf(v1.z) | ((unsigned)f2bf(v1.w) << 16);
            *(uint4*)(As + r * 128 + ((c ^ (r & 15)) << 3)) = o;
        }
    }
    __syncthreads();

    const int m16  = lane & 15;
    const int quad = lane >> 4;

    f32x4 acc[7];
    #pragma unroll
    for (int t = 0; t < 7; ++t) acc[t] = (f32x4){0.f, 0.f, 0.f, 0.f};

    short8 afr[4];
    {
        const unsigned short* Ab = As + (wv * 16 + m16) * 128;
        #pragma unroll
        for (int ks = 0; ks < 4; ++ks)
            afr[ks] = *(const short8*)(Ab + (((ks * 4 + quad) ^ m16) << 3));
    }

    #pragma unroll
    for (int t = 0; t < 7; ++t) {
        if (t >= ntile) break;
        const unsigned short* Bb = Bs + (t * 16 + m16) * 128;
        #pragma unroll
        for (int ks = 0; ks < 4; ++ks) {
            short8 bfr = *(const short8*)(Bb + (((ks * 4 + quad) ^ m16) << 3));
            acc[t] = __builtin_amdgcn_mfma_f32_16x16x32_bf16(afr[ks], bfr, acc[t], 0, 0, 0);
        }
    }

    // out tiles (y=3, local t=4,5 = abs cols 384..415): direct fp32 stores
    if (yb == 3) {
        #pragma unroll
        for (int t = 4; t < 6; ++t) {
            int col = 320 + t * 16 + m16;
            float bb = biasc[col];
            #pragma unroll
            for (int r = 0; r < 4; ++r) {
                int grow = row0 + wv * 16 + quad * 4 + r;
                if (grow < NN) out[(size_t)grow * OUTC + (col - 384)] = acc[t][r] + bb;
            }
        }
    }

    __syncthreads();   // all MFMA reads of As done -> safe to overwrite with Cs

    const int ntf  = (yb == 3) ? 4 : ntile;                     // f16 tiles to LDS
    const int cstr = (yb & 1) ? ((yb == 1) ? 104 : 72) : 120;   // pad: <=2-way conflicts
    #pragma unroll
    for (int t = 0; t < 7; ++t) {
        if (t >= ntf) break;
        int col = base + t * 16 + m16;
        float bb = biasc[col];
        #pragma unroll
        for (int r = 0; r < 4; ++r) {
            int lrow = wv * 16 + quad * 4 + r;
            Cs[lrow * cstr + t * 16 + m16] = f2h(acc[t][r] + bb);
        }
    }
    __syncthreads();

    // coalesced copy-out: 16B LDS chunks -> ms / erh (all full 16B stores)
    if (yb == 0)      copy_out<14, 120, 0 >(Cs, row0, tid, ms, erh);
    else if (yb == 1) copy_out<12, 104, 14>(Cs, row0, tid, ms, erh);
    else if (yb == 2) copy_out<14, 120, 26>(Cs, row0, tid, ms, erh);
    else              copy_out<8,  72,  40>(Cs, row0, tid, ms, erh);

    // edge bucketing TAIL: atomic + dependent random store overlap other blocks
    if (e < EE) {
        int r = atomicAdd(&counts[(size_t)ed * CSTRIDE], 1);
        if (r < CAP) srcbuck[(size_t)ed * CAP + r] = es;
    }
}

// ---------------- fused edge phase: one wave/node, 32 lanes/edge, ONE uint4 gather
// leaky(z) = 0.6z + 0.4|z|  =>  s = 0.6*dot(at,z) + 0.4*dot(at,|z|)
// ms row: group li (16B) = mut ch 4li..4li+3 | self ch 4li..4li+3
__device__ __forceinline__ void edgeP(
    const uint4 v, const f16x2 er01, const f16x2 er23,
    const f16x2 at01, const f16x2 at23,
    float& l, float& a0, float& a1, float& a2, float& a3)
{
    f16x2 z01 = bch(v.x) + er01;
    f16x2 z23 = bch(v.y) + er23;
    float s1 = __builtin_amdgcn_fdot2(at01, z01, 0.f, false);
    s1 = __builtin_amdgcn_fdot2(at23, z23, s1, false);
    float s2 = __builtin_amdgcn_fdot2(at01, habs2(z01), 0.f, false);
    s2 = __builtin_amdgcn_fdot2(at23, habs2(z23), s2, false);
    float s = fmaf(0.6f, s1, 0.4f * s2);
    s += __shfl_xor(s, 1, 64);
    s += __shfl_xor(s, 2, 64);
    s += __shfl_xor(s, 4, 64);
    float p = __expf(s);
    l += p;
    fl2 c01 = __builtin_convertvector(bch(v.z), fl2);
    fl2 c23 = __builtin_convertvector(bch(v.w), fl2);
    a0 = fmaf(p, c01.x, a0);
    a1 = fmaf(p, c01.y, a1);
    a2 = fmaf(p, c23.x, a2);
    a3 = fmaf(p, c23.y, a3);
}

__global__ __launch_bounds__(256) void node_agg8(
    const unsigned short* __restrict__ ms,     // [N][256] f16 interleaved mut|self
    const unsigned short* __restrict__ erh,    // [N][128] f16
    const unsigned short* __restrict__ ath,    // [128] f16
    const int* __restrict__ counts,            // [N*CSTRIDE], line-padded
    const int* __restrict__ srcbuck,           // [N][CAP]
    float* __restrict__ out)
{
    const int n = blockIdx.x * 4 + (threadIdx.x >> 6);
    if (n >= NN) return;
    const int lane = threadIdx.x & 63;
    const int half = lane >> 5;          // contiguous half of the bucket
    const int li   = lane & 31;          // channel group: 4li..4li+3

    uint2 aw = *(const uint2*)(ath + li * 4);
    uint2 ew = *(const uint2*)(erh + (size_t)n * HF + li * 4);
    const f16x2 at01 = bch(aw.x), at23 = bch(aw.y);
    const f16x2 er01 = bch(ew.x), er23 = bch(ew.y);

    const int beg = n * CAP;
    int deg = counts[(size_t)n * CSTRIDE];
    deg = (deg > CAP) ? CAP : deg;
    const int cnt0 = (deg + 1) >> 1;
    const int st  = beg + (half ? cnt0 : 0);
    const int cnt = half ? (deg - cnt0) : cnt0;

    float l = 0.f, a0 = 0.f, a1 = 0.f, a2 = 0.f, a3 = 0.f;

    int k = 0;
    for (; k + 4 <= cnt; k += 4) {
        int i0 = srcbuck[st + k];
        int i1 = srcbuck[st + k + 1];
        int i2 = srcbuck[st + k + 2];
        int i3 = srcbuck[st + k + 3];
        uint4 v0 = *(const uint4*)(ms + (size_t)i0 * 256 + li * 8);
        uint4 v1 = *(const uint4*)(ms + (size_t)i1 * 256 + li * 8);
        uint4 v2 = *(const uint4*)(ms + (size_t)i2 * 256 + li * 8);
        uint4 v3 = *(const uint4*)(ms + (size_t)i3 * 256 + li * 8);
        edgeP(v0, er01, er23, at01, at23, l, a0, a1, a2, a3);
        edgeP(v1, er01, er23, at01, at23, l, a0, a1, a2, a3);
        edgeP(v2, er01, er23, at01, at23, l, a0, a1, a2, a3);
        edgeP(v3, er01, er23, at01, at23, l, a0, a1, a2, a3);
    }
    for (; k < cnt; ++k) {
        int i0 = srcbuck[st + k];
        uint4 v0 = *(const uint4*)(ms + (size_t)i0 * 256 + li * 8);
        edgeP(v0, er01, er23, at01, at23, l, a0, a1, a2, a3);
    }

    l  += __shfl_xor(l,  32, 64);
    a0 += __shfl_xor(a0, 32, 64);
    a1 += __shfl_xor(a1, 32, 64);
    a2 += __shfl_xor(a2, 32, 64);
    a3 += __shfl_xor(a3, 32, 64);

    if (half == 0) {
        float inv = (l > 0.f) ? __frcp_rn(l) : 0.f;
        float4 r = make_float4(a0 * inv, a1 * inv, a2 * inv, a3 * inv);
        *(float4*)(out + (size_t)n * OUTC + FF + li * 4) = r;
    }
}

extern "C" void kernel_launch(void* const* d_in, const int* in_sizes, int n_in,
                              void* d_out, int out_size, void* d_ws, size_t ws_size,
                              hipStream_t stream) {
    const float* feat   = (const float*)d_in[0];
    const float* W_src  = (const float*)d_in[1];
    const float* b_src  = (const float*)d_in[2];
    const float* W_dst  = (const float*)d_in[3];
    const float* b_dst  = (const float*)d_in[4];
    const float* W_self = (const float*)d_in[5];
    const float* b_self = (const float*)d_in[6];
    const float* W_lin  = (const float*)d_in[7];
    const float* b_lin  = (const float*)d_in[8];
    const float* attn   = (const float*)d_in[9];
    const int*   src    = (const int*)d_in[10];
    const int*   dst    = (const int*)d_in[11];
    float* out = (float*)d_out;

    // workspace carve-up
    unsigned short* ms    = (unsigned short*)d_ws;                  // N*256 f16 (mut|self interleaved)
    unsigned short* erh   = ms  + (size_t)NN * 256;                 // N*128 f16
    unsigned short* WbT   = erh + (size_t)NN * HF;                  // 416*128 bf16
    unsigned short* ath   = WbT + 416 * 128;                        // 128 f16
    float* biasc   = (float*)(ath + 128);                           // 416 fp32
    int*   counts  = (int*)(biasc + 416);                           // N*CSTRIDE ints (3.2MB, line-padded)
    int*   srcbuck = counts + (size_t)NN * CSTRIDE;                 // N*CAP ints (12.8MB)

    // prep: weights transpose/swizzle + bias + attn + padded-counts zeroing
    prep_w<<<208, 256, 0, stream>>>(W_src, b_src, W_dst, b_dst, W_self, b_self,
                                    W_lin, b_lin, attn, WbT, biasc, ath, counts);

    // fused projection GEMM + edge bucketing (loads at top, atomic+scatter at tail)
    {
        dim3 grid(782, 4);   // 782 row-blocks x 4 col-splits; 3128*256 covers E edges
        gemm_hist<<<grid, 256, 0, stream>>>(feat, WbT, biasc, src, dst,
                                            ms, erh, out, counts, srcbuck);
    }

    // fused edge phase: one wave per node, 32 lanes/edge, single uint4 gather
    node_agg8<<<(NN + 3) / 4, 256, 0, stream>>>(ms, erh, ath,
                                                counts, srcbuck, out);
}

// Round 7
// 202.826 us; speedup vs baseline: 1.0027x; 1.0027x over previous
//
#include <hip/hip_runtime.h>
#include <hip/hip_bf16.h>

// Problem constants (from reference)
#define NN 50000
#define EE 800000
#define INF_ 128
#define HH 4
#define FF 32
#define HF 128          // H*F
#define OUTC 160        // (H+1)*F per node
#define NEG_SLOPE 0.2f

#define CAP 64          // per-node bucket capacity; P(deg>64 | lambda=16) ~ 1e-19
#define CSTRIDE 16      // counts padded: one counter per 64B line

typedef __attribute__((ext_vector_type(8))) short short8;
typedef __attribute__((ext_vector_type(4))) float f32x4;
typedef _Float16 f16x2 __attribute__((ext_vector_type(2)));
typedef float fl2 __attribute__((ext_vector_type(2)));

// fp32 -> bf16 bits, round-to-nearest-even
__device__ __forceinline__ unsigned short f2bf(float f) {
    union { float f; unsigned u; } in; in.f = f;
    unsigned u = in.u;
    u += 0x7fffu + ((u >> 16) & 1u);
    return (unsigned short)(u >> 16);
}
__device__ __forceinline__ unsigned short f2h(float f) {
    _Float16 h = (_Float16)f;
    return __builtin_bit_cast(unsigned short, h);
}
__device__ __forceinline__ f16x2 bch(unsigned u) {
    return __builtin_bit_cast(f16x2, u);
}
__device__ __forceinline__ f16x2 habs2(f16x2 v) {
    unsigned u = __builtin_bit_cast(unsigned, v) & 0x7FFF7FFFu;
    return __builtin_bit_cast(f16x2, u);
}

// async global->LDS 16B copy: LDS dest = wave-uniform base + lane*16
__device__ __forceinline__ void async_cp16(const void* g, void* l) {
    __builtin_amdgcn_global_load_lds(
        (const __attribute__((address_space(1))) void*)g,
        (__attribute__((address_space(3))) void*)l, 16, 0, 0);
}

// ---------------- prep: weights transpose/swizzle + bias + attn + counts=0 -------
// Column order (n of 416), chosen so the edge-phase layout is produced directly:
//   n in [0,256):  pair-group g=n>>3, j=n&7; j<4 -> mut ch 4g+j, j>=4 -> self ch 4g+(j-4)
//   n in [256,384): er ch n-256
//   n in [384,416): lin ch n-384
__global__ __launch_bounds__(256) void prep_w(
    const float* __restrict__ W0, const float* __restrict__ b0,   // W_src_mut
    const float* __restrict__ W1, const float* __restrict__ b1,   // W_dst_mut (er)
    const float* __restrict__ W2, const float* __restrict__ b2,   // W_self
    const float* __restrict__ W3, const float* __restrict__ b3,   // W_lin
    const float* __restrict__ attn,
    unsigned short* __restrict__ WbT, float* __restrict__ biasc,
    unsigned short* __restrict__ ath, int* __restrict__ counts)
{
    int idx = blockIdx.x * 256 + threadIdx.x;   // 208 blocks -> 416*128 = 53248
    if (idx < NN) {
        // zero this node's private counter line (64B) -- fused memset
        uint4 z = make_uint4(0, 0, 0, 0);
        uint4* p = (uint4*)(counts + (size_t)idx * CSTRIDE);
        p[0] = z; p[1] = z; p[2] = z; p[3] = z;
    }
    int n = idx >> 7, k = idx & 127;
    float v;
    if (n < 256) {
        int g = n >> 3, j = n & 7;
        int ch = g * 4 + (j & 3);
        v = (j < 4) ? W0[k * 128 + ch] : W2[k * 128 + ch];
    } else if (n < 384) {
        v = W1[k * 128 + (n - 256)];
    } else {
        v = W3[k * 32 + (n - 384)];
    }
    int phys = (((k >> 3) ^ (n & 15)) << 3) | (k & 7);
    WbT[n * 128 + phys] = f2bf(v);
    if (idx < 416) {
        float bv;
        if (idx < 256) {
            int g = idx >> 3, j = idx & 7;
            int ch = g * 4 + (j & 3);
            bv = (j < 4) ? b0[ch] : b2[ch];
        } else if (idx < 384) {
            bv = b1[idx - 256];
        } else {
            bv = b3[idx - 384];
        }
        biasc[idx] = bv;
    }
    if (idx < 128) ath[idx] = f2h(attn[idx]);
}

// ---------------- fused GEMM + edge bucketing ------------------------------------
// grid (782, 4). Column split 112/96/112/96 -> LDS 44KB -> 3 blocks/CU.
// Edge handling is SPLIT: src/dst loads issued at block top (latency hidden under
// staging), atomicAdd + dependent random bucket store at the kernel TAIL so the
// atomic's latency never sits in front of the block's own MFMA barrier.
// abs 16B chunk ca: 0..31 -> ms[N][256] (interleaved mut|self), 32..47 -> erh,
// 48..51 -> out fp32 (handled directly from acc in y=3).

template<int CPR, int CSTR, int CA0>
__device__ __forceinline__ void copy_out(
    const unsigned short* Cs, int row0, int tid,
    unsigned short* __restrict__ ms, unsigned short* __restrict__ erh)
{
    for (int c = tid; c < 64 * CPR; c += 256) {
        int row = c / CPR, c16 = c - row * CPR;
        int grow = row0 + row;
        if (grow >= NN) continue;
        uint4 v = *(const uint4*)(Cs + row * CSTR + c16 * 8);
        int ca = CA0 + c16;
        if (ca < 32) *(uint4*)(ms  + (size_t)grow * 256 + ca * 8) = v;
        else         *(uint4*)(erh + (size_t)grow * 128 + (ca - 32) * 8) = v;
    }
}

__global__ __launch_bounds__(256) void gemm_hist(
    const float* __restrict__ feat,
    const unsigned short* __restrict__ WbT,
    const float* __restrict__ biasc,
    const int* __restrict__ src, const int* __restrict__ dst,
    unsigned short* __restrict__ ms, unsigned short* __restrict__ erh,
    float* __restrict__ out,
    int* __restrict__ counts, int* __restrict__ srcbuck)
{
    __shared__ __align__(16) char lds[16384 + 28672];   // As 16KB | Bs 28KB
    unsigned short* As = (unsigned short*)lds;
    unsigned short* Bs = (unsigned short*)(lds + 16384);
    unsigned short* Cs = (unsigned short*)lds;           // aliases As post-MFMA (<=15.4KB)

    const int tid  = threadIdx.x;
    const int wv   = tid >> 6;
    const int lane = tid & 63;
    const int row0 = blockIdx.x * 64;
    const int yb   = blockIdx.y;

    // edge prefetch: issue src/dst loads NOW, consume at kernel tail
    const int e = (yb * 782 + blockIdx.x) * 256 + tid;
    int ed = 0, es = 0;
    if (e < EE) { ed = dst[e]; es = src[e]; }
    asm volatile("" :: "v"(ed), "v"(es));   // pin: force loads issued here

    const int ntile = (yb & 1) ? 6 : 7;                       // 16-col tiles this block
    const int base  = (yb == 0) ? 0 : (yb == 1) ? 112 : (yb == 2) ? 208 : 320;

    // stage B (async; WbT is pre-swizzled, LDS linear preserves swizzle)
    {
        const char* g = (const char*)(WbT + (size_t)base * 128);
        #pragma unroll
        for (int it = 0; it < 7; ++it) {
            if (it < ntile) {
                int seg = wv * ntile + it;
                async_cp16(g + seg * 1024 + lane * 16, (char*)Bs + seg * 1024);
            }
        }
    }
    // stage A: fp32 feat -> bf16 in regs, XOR-swizzled 16B chunks into LDS
    {
        #pragma unroll
        for (int i = 0; i < 4; ++i) {
            int idx = i * 256 + tid;           // 1024 chunks = 64 rows x 16
            int r = idx >> 4, c = idx & 15;
            int grow = row0 + r;
            float4 v0 = make_float4(0.f, 0.f, 0.f, 0.f), v1 = v0;
            if (grow < NN) {
                const float4* fp = (const float4*)(feat + (size_t)grow * 128 + c * 8);
                v0 = fp[0]; v1 = fp[1];
            }
            uint4 o;
            o.x = (unsigned)f2bf(v0.x) | ((unsigned)f2bf(v0.y) << 16);
            o.y = (unsigned)f2bf(v0.z) | ((unsigned)f2bf(v0.w) << 16);
            o.z = (unsigned)f2bf(v1.x) | ((unsigned)f2bf(v1.y) << 16);
            o.w = (unsigned)f2bf(v1.z) | ((unsigned)f2bf(v1.w) << 16);
            *(uint4*)(As + r * 128 + ((c ^ (r & 15)) << 3)) = o;
        }
    }
    __syncthreads();

    const int m16  = lane & 15;
    const int quad = lane >> 4;

    f32x4 acc[7];
    #pragma unroll
    for (int t = 0; t < 7; ++t) acc[t] = (f32x4){0.f, 0.f, 0.f, 0.f};

    short8 afr[4];
    {
        const unsigned short* Ab = As + (wv * 16 + m16) * 128;
        #pragma unroll
        for (int ks = 0; ks < 4; ++ks)
            afr[ks] = *(const short8*)(Ab + (((ks * 4 + quad) ^ m16) << 3));
    }

    #pragma unroll
    for (int t = 0; t < 7; ++t) {
        if (t >= ntile) break;
        const unsigned short* Bb = Bs + (t * 16 + m16) * 128;
        #pragma unroll
        for (int ks = 0; ks < 4; ++ks) {
            short8 bfr = *(const short8*)(Bb + (((ks * 4 + quad) ^ m16) << 3));
            acc[t] = __builtin_amdgcn_mfma_f32_16x16x32_bf16(afr[ks], bfr, acc[t], 0, 0, 0);
        }
    }

    // out tiles (y=3, local t=4,5 = abs cols 384..415): direct fp32 stores
    if (yb == 3) {
        #pragma unroll
        for (int t = 4; t < 6; ++t) {
            int col = 320 + t * 16 + m16;
            float bb = biasc[col];
            #pragma unroll
            for (int r = 0; r < 4; ++r) {
                int grow = row0 + wv * 16 + quad * 4 + r;
                if (grow < NN) out[(size_t)grow * OUTC + (col - 384)] = acc[t][r] + bb;
            }
        }
    }

    __syncthreads();   // all MFMA reads of As done -> safe to overwrite with Cs

    const int ntf  = (yb == 3) ? 4 : ntile;                     // f16 tiles to LDS
    const int cstr = (yb & 1) ? ((yb == 1) ? 104 : 72) : 120;   // pad: <=2-way conflicts
    #pragma unroll
    for (int t = 0; t < 7; ++t) {
        if (t >= ntf) break;
        int col = base + t * 16 + m16;
        float bb = biasc[col];
        #pragma unroll
        for (int r = 0; r < 4; ++r) {
            int lrow = wv * 16 + quad * 4 + r;
            Cs[lrow * cstr + t * 16 + m16] = f2h(acc[t][r] + bb);
        }
    }
    __syncthreads();

    // coalesced copy-out: 16B LDS chunks -> ms / erh (all full 16B stores)
    if (yb == 0)      copy_out<14, 120, 0 >(Cs, row0, tid, ms, erh);
    else if (yb == 1) copy_out<12, 104, 14>(Cs, row0, tid, ms, erh);
    else if (yb == 2) copy_out<14, 120, 26>(Cs, row0, tid, ms, erh);
    else              copy_out<8,  72,  40>(Cs, row0, tid, ms, erh);

    // edge bucketing TAIL: atomic + dependent random store overlap other blocks
    if (e < EE) {
        int r = atomicAdd(&counts[(size_t)ed * CSTRIDE], 1);
        if (r < CAP) srcbuck[(size_t)ed * CAP + r] = es;
    }
}

// ---------------- fused edge phase: one wave/node, 32 lanes/edge -----------------
// Index preload: all 64 bucket slots in ONE coalesced load; edge k's index obtained
// via __shfl (no memory chain). Ping-pong A/B batches of 4 -> ~8 gathers in flight.
// Batches padded with clamped duplicate indices; masked via p = valid ? exp : 0.
// leaky(z) = 0.6z + 0.4|z|  =>  s = 0.6*dot(at,z) + 0.4*dot(at,|z|)
// ms row: group li (16B) = mut ch 4li..4li+3 | self ch 4li..4li+3

__device__ __forceinline__ int bgeti(int idxv, int stL, int cnt, int k) {
    int kk = (k < cnt) ? k : (cnt - 1);          // clamp to last valid slot
    return __shfl(idxv, stL + kk, 64);
}
__device__ __forceinline__ uint4 ldms(const unsigned short* __restrict__ ms,
                                      int i, int li) {
    return *(const uint4*)(ms + (size_t)i * 256 + li * 8);
}

__device__ __forceinline__ void edgeM(
    const uint4 v, const bool valid,
    const f16x2 er01, const f16x2 er23,
    const f16x2 at01, const f16x2 at23,
    float& l, float& a0, float& a1, float& a2, float& a3)
{
    f16x2 z01 = bch(v.x) + er01;
    f16x2 z23 = bch(v.y) + er23;
    float s1 = __builtin_amdgcn_fdot2(at01, z01, 0.f, false);
    s1 = __builtin_amdgcn_fdot2(at23, z23, s1, false);
    float s2 = __builtin_amdgcn_fdot2(at01, habs2(z01), 0.f, false);
    s2 = __builtin_amdgcn_fdot2(at23, habs2(z23), s2, false);
    float s = fmaf(0.6f, s1, 0.4f * s2);
    s += __shfl_xor(s, 1, 64);
    s += __shfl_xor(s, 2, 64);
    s += __shfl_xor(s, 4, 64);
    float p = valid ? __expf(s) : 0.f;
    l += p;
    fl2 c01 = __builtin_convertvector(bch(v.z), fl2);
    fl2 c23 = __builtin_convertvector(bch(v.w), fl2);
    a0 = fmaf(p, c01.x, a0);
    a1 = fmaf(p, c01.y, a1);
    a2 = fmaf(p, c23.x, a2);
    a3 = fmaf(p, c23.y, a3);
}

__global__ __launch_bounds__(256) void node_agg9(
    const unsigned short* __restrict__ ms,     // [N][256] f16 interleaved mut|self
    const unsigned short* __restrict__ erh,    // [N][128] f16
    const unsigned short* __restrict__ ath,    // [128] f16
    const int* __restrict__ counts,            // [N*CSTRIDE], line-padded
    const int* __restrict__ srcbuck,           // [N][CAP]
    float* __restrict__ out)
{
    const int n = blockIdx.x * 4 + (threadIdx.x >> 6);
    if (n >= NN) return;
    const int lane = threadIdx.x & 63;
    const int half = lane >> 5;          // contiguous half of the bucket
    const int li   = lane & 31;          // channel group: 4li..4li+3

    // one coalesced 256B load: every bucket slot of this node into lane registers
    const int idxv = srcbuck[n * CAP + lane];
    int deg = counts[(size_t)n * CSTRIDE];
    deg = (deg > CAP) ? CAP : deg;

    uint2 aw = *(const uint2*)(ath + li * 4);
    uint2 ew = *(const uint2*)(erh + (size_t)n * HF + li * 4);
    const f16x2 at01 = bch(aw.x), at23 = bch(aw.y);
    const f16x2 er01 = bch(ew.x), er23 = bch(ew.y);

    const int cnt0 = (deg + 1) >> 1;
    const int stL  = half ? cnt0 : 0;
    const int cnt  = half ? (deg - cnt0) : cnt0;

    float l = 0.f, a0 = 0.f, a1 = 0.f, a2 = 0.f, a3 = 0.f;

    if (cnt > 0) {
        const int nb = (cnt + 3) >> 2;   // 4-edge batches (<=8)
        uint4 A0 = ldms(ms, bgeti(idxv, stL, cnt, 0), li);
        uint4 A1 = ldms(ms, bgeti(idxv, stL, cnt, 1), li);
        uint4 A2 = ldms(ms, bgeti(idxv, stL, cnt, 2), li);
        uint4 A3 = ldms(ms, bgeti(idxv, stL, cnt, 3), li);
        for (int b = 0; b < nb; b += 2) {
            const int kB = (b + 1) * 4;
            const bool hasB = (b + 1) < nb;
            uint4 B0, B1, B2, B3;
            if (hasB) {
                B0 = ldms(ms, bgeti(idxv, stL, cnt, kB + 0), li);
                B1 = ldms(ms, bgeti(idxv, stL, cnt, kB + 1), li);
                B2 = ldms(ms, bgeti(idxv, stL, cnt, kB + 2), li);
                B3 = ldms(ms, bgeti(idxv, stL, cnt, kB + 3), li);
            }
            const int kA = b * 4;
            edgeM(A0, kA + 0 < cnt, er01, er23, at01, at23, l, a0, a1, a2, a3);
            edgeM(A1, kA + 1 < cnt, er01, er23, at01, at23, l, a0, a1, a2, a3);
            edgeM(A2, kA + 2 < cnt, er01, er23, at01, at23, l, a0, a1, a2, a3);
            edgeM(A3, kA + 3 < cnt, er01, er23, at01, at23, l, a0, a1, a2, a3);
            if (!hasB) break;
            const int kN = (b + 2) * 4;
            if (b + 2 < nb) {
                A0 = ldms(ms, bgeti(idxv, stL, cnt, kN + 0), li);
                A1 = ldms(ms, bgeti(idxv, stL, cnt, kN + 1), li);
                A2 = ldms(ms, bgeti(idxv, stL, cnt, kN + 2), li);
                A3 = ldms(ms, bgeti(idxv, stL, cnt, kN + 3), li);
            }
            edgeM(B0, kB + 0 < cnt, er01, er23, at01, at23, l, a0, a1, a2, a3);
            edgeM(B1, kB + 1 < cnt, er01, er23, at01, at23, l, a0, a1, a2, a3);
            edgeM(B2, kB + 2 < cnt, er01, er23, at01, at23, l, a0, a1, a2, a3);
            edgeM(B3, kB + 3 < cnt, er01, er23, at01, at23, l, a0, a1, a2, a3);
        }
    }

    l  += __shfl_xor(l,  32, 64);
    a0 += __shfl_xor(a0, 32, 64);
    a1 += __shfl_xor(a1, 32, 64);
    a2 += __shfl_xor(a2, 32, 64);
    a3 += __shfl_xor(a3, 32, 64);

    if (half == 0) {
        float inv = (l > 0.f) ? __frcp_rn(l) : 0.f;
        float4 r = make_float4(a0 * inv, a1 * inv, a2 * inv, a3 * inv);
        *(float4*)(out + (size_t)n * OUTC + FF + li * 4) = r;
    }
}

extern "C" void kernel_launch(void* const* d_in, const int* in_sizes, int n_in,
                              void* d_out, int out_size, void* d_ws, size_t ws_size,
                              hipStream_t stream) {
    const float* feat   = (const float*)d_in[0];
    const float* W_src  = (const float*)d_in[1];
    const float* b_src  = (const float*)d_in[2];
    const float* W_dst  = (const float*)d_in[3];
    const float* b_dst  = (const float*)d_in[4];
    const float* W_self = (const float*)d_in[5];
    const float* b_self = (const float*)d_in[6];
    const float* W_lin  = (const float*)d_in[7];
    const float* b_lin  = (const float*)d_in[8];
    const float* attn   = (const float*)d_in[9];
    const int*   src    = (const int*)d_in[10];
    const int*   dst    = (const int*)d_in[11];
    float* out = (float*)d_out;

    // workspace carve-up
    unsigned short* ms    = (unsigned short*)d_ws;                  // N*256 f16 (mut|self interleaved)
    unsigned short* erh   = ms  + (size_t)NN * 256;                 // N*128 f16
    unsigned short* WbT   = erh + (size_t)NN * HF;                  // 416*128 bf16
    unsigned short* ath   = WbT + 416 * 128;                        // 128 f16
    float* biasc   = (float*)(ath + 128);                           // 416 fp32
    int*   counts  = (int*)(biasc + 416);                           // N*CSTRIDE ints (3.2MB, line-padded)
    int*   srcbuck = counts + (size_t)NN * CSTRIDE;                 // N*CAP ints (12.8MB)

    // prep: weights transpose/swizzle + bias + attn + padded-counts zeroing
    prep_w<<<208, 256, 0, stream>>>(W_src, b_src, W_dst, b_dst, W_self, b_self,
                                    W_lin, b_lin, attn, WbT, biasc, ath, counts);

    // fused projection GEMM + edge bucketing (loads at top, atomic+scatter at tail)
    {
        dim3 grid(782, 4);   // 782 row-blocks x 4 col-splits; 3128*256 covers E edges
        gemm_hist<<<grid, 256, 0, stream>>>(feat, WbT, biasc, src, dst,
                                            ms, erh, out, counts, srcbuck);
    }

    // fused edge phase: index-preload + ping-pong pipelined gathers
    node_agg9<<<(NN + 3) / 4, 256, 0, stream>>>(ms, erh, ath,
                                                counts, srcbuck, out);
}